// Round 5
// baseline (199.332 us; speedup 1.0000x reference)
//
#include <hip/hip_runtime.h>
#include <math.h>

#define NJ 960           // tail columns (global 64..1023)
#define NSRC 896         // tail sources (global 128..1023)
#define NWARM 25

typedef unsigned long long u64;
typedef unsigned int u32;

// ws layout (u64 indices):
//   RK[896]  : tag | (rE | rI<<16)
//   CT[960]  : tag | (cntE | cntI<<16)
//   HD[960]  : tag | float bits of hd[j]
//   BSP[480] : packed pair (base[2w] | base[2w+1]<<32) — ordered by DN rel/acq
//   DN[1]    : tag — DONE flag (release-published by scan)
#define RK_O 0u
#define CT_O 896u
#define HD_O 1856u
#define BSP_O 2816u
#define DN_O 3776u

#define TAG_RK 0x524B0001u
#define TAG_CT 0x43540001u
#define TAG_HD 0x48440001u
#define TAG_DN 0x444E0001u

__device__ __forceinline__ void ast(u64* p, u64 v) {
  __hip_atomic_store(p, v, __ATOMIC_RELAXED, __HIP_MEMORY_SCOPE_AGENT);
}
__device__ __forceinline__ u64 ald(const u64* p) {
  return __hip_atomic_load(p, __ATOMIC_RELAXED, __HIP_MEMORY_SCOPE_AGENT);
}
__device__ __forceinline__ u32 poll32(const u64* p, u32 tag) {
  u64 v = ald(p);
  while ((u32)(v >> 32) != tag) { __builtin_amdgcn_s_sleep(1); v = ald(p); }
  return (u32)v;
}

struct ScanSm {
  float yl[NJ];
  float2 scanE[1024];
  float2 scanI[1024];
  float4 wtot[4];
  float ssw[4];
};
struct BatSm {
  float At[64][16];     // transposed input tile (16 rows); reads wave-broadcast
  union {
    float Wl[16][512];  // weight tile (live during MMA)
    float bch[NJ];      // base bias (live after DN; Wl dead) — union saves 4 KB
  };
  float4 Ek4[64];       // {e^{+be}, e^{-be}, e^{+bi}, e^{-bi}} per head source
  float2 Ei2[64];       // raw {e_k, i_k}
};
// BatSm = 4096 + 32768 + 1024 + 512 = 38400 B -> 38.9 KB rounded -> 4 blocks/CU
// -> 1024 slots = whole grid resident, no post-DN tail pass.

// Fused kernel, grid 1024:
//   block 0      : warmup scan (publishes BSP+DN)
//   blocks 1..30 : prep (ranks/counts/hd) then batch
//   blocks 1..1023: batch tile = blockIdx-1; block 1 also does tile 1023.
// Non-prep batch blocks sleep 13-37 us (staggered) so prep+scan start on a
// quiet GPU; batch MMA then smears under the ~80 us scan. Sleep is a pure
// perf hint: dependency graph (scan<-prep, batch<-scan) stays acyclic.
__global__ __launch_bounds__(256, 2) void grn_all(
    const float* __restrict__ inp, const float* __restrict__ ident,
    const float* __restrict__ enh, const float* __restrict__ inh,
    const float* __restrict__ beta, const float* __restrict__ delta,
    void* __restrict__ wsv, float* __restrict__ out) {
  __shared__ __align__(16) char smraw[(sizeof(BatSm) > sizeof(ScanSm))
                                          ? sizeof(BatSm) : sizeof(ScanSm)];
  u64* RK = (u64*)wsv + RK_O;
  u64* CT = (u64*)wsv + CT_O;
  u64* HD = (u64*)wsv + HD_O;
  u64* BSP = (u64*)wsv + BSP_O;
  u64* DN = (u64*)wsv + DN_O;

  const int tid = threadIdx.x;
  const float bb = beta[0];
  const float dN = delta[0] / 1024.0f;

  if (blockIdx.x == 0) {
    // ---------------- scan block (proven code, unchanged) ----------------
    ScanSm& S = *(ScanSm*)smraw;
    const int lane = tid & 63, wvid = tid >> 6;

    int rE[4], rI[4];
    if (tid < 224) {
      #pragma unroll
      for (int s = 0; s < 4; ++s) {
        u32 v = poll32(&RK[4 * tid + s], TAG_RK);
        rE[s] = v & 0xFFFF; rI[s] = v >> 16;
      }
    }
    int cE[4], cI[4];
    float hd[4], fm[4], fp[4];
    if (tid < 240) {
      #pragma unroll
      for (int c = 0; c < 4; ++c) {
        u32 v = poll32(&CT[4 * tid + c], TAG_CT);
        cE[c] = v & 0xFFFF; cI[c] = v >> 16;
        hd[c] = __uint_as_float(poll32(&HD[4 * tid + c], TAG_HD));
        float cj = ident[64 + 4 * tid + c];
        fm[c] = expf(-bb * cj); fp[c] = expf(bb * cj);
      }
    }
    float EP[4], EN[4], IP[4], IN2[4];
    if (tid < 224) {
      #pragma unroll
      for (int s = 0; s < 4; ++s) {
        float e = enh[128 + 4 * tid + s], i2 = inh[128 + 4 * tid + s];
        EP[s] = expf(bb * e);  EN[s] = expf(-bb * e);
        IP[s] = expf(bb * i2); IN2[s] = expf(-bb * i2);
      }
    }
    float y_own[4] = {1.0f / 1024.0f, 1.0f / 1024.0f, 1.0f / 1024.0f, 1.0f / 1024.0f};
    if (tid < 240) {
      #pragma unroll
      for (int c = 0; c < 4; ++c) S.yl[4 * tid + c] = 1.0f / 1024.0f;
    }
    __syncthreads();

    for (int t = 0; t <= NWARM; ++t) {
      if (tid == 0) {
        S.scanE[0] = make_float2(0.f, 0.f);
        S.scanI[0] = make_float2(0.f, 0.f);
      }
      if (tid >= 224) {
        #pragma unroll
        for (int c = 0; c < 4; ++c) {
          int p = 4 * tid + c;
          if (p > NSRC) {
            S.scanE[p] = make_float2(0.f, 0.f);
            S.scanI[p] = make_float2(0.f, 0.f);
          }
        }
      }
      if (tid < 224) {
        #pragma unroll
        for (int s = 0; s < 4; ++s) {
          float ym = S.yl[64 + 4 * tid + s];
          S.scanE[rE[s] + 1] = make_float2(ym * EP[s], ym * EN[s]);
          S.scanI[rI[s] + 1] = make_float2(ym * IP[s], ym * IN2[s]);
        }
      }
      __syncthreads();

      float2 e0 = S.scanE[4 * tid], e1 = S.scanE[4 * tid + 1],
             e2 = S.scanE[4 * tid + 2], e3 = S.scanE[4 * tid + 3];
      float2 i0 = S.scanI[4 * tid], i1 = S.scanI[4 * tid + 1],
             i2v = S.scanI[4 * tid + 2], i3 = S.scanI[4 * tid + 3];
      e1.x += e0.x; e1.y += e0.y; e2.x += e1.x; e2.y += e1.y; e3.x += e2.x; e3.y += e2.y;
      i1.x += i0.x; i1.y += i0.y; i2v.x += i1.x; i2v.y += i1.y; i3.x += i2v.x; i3.y += i2v.y;
      float4 tot = make_float4(e3.x, e3.y, i3.x, i3.y);
      float4 inc = tot;
      #pragma unroll
      for (int off = 1; off < 64; off <<= 1) {
        float ox = __shfl_up(inc.x, off, 64);
        float oy = __shfl_up(inc.y, off, 64);
        float oz = __shfl_up(inc.z, off, 64);
        float ow = __shfl_up(inc.w, off, 64);
        if (lane >= off) { inc.x += ox; inc.y += oy; inc.z += oz; inc.w += ow; }
      }
      if (lane == 63) S.wtot[wvid] = inc;
      __syncthreads();
      float4 exc = make_float4(inc.x - tot.x, inc.y - tot.y,
                               inc.z - tot.z, inc.w - tot.w);
      #pragma unroll
      for (int w = 0; w < 3; ++w)
        if (w < wvid) {
          float4 p = S.wtot[w];
          exc.x += p.x; exc.y += p.y; exc.z += p.z; exc.w += p.w;
        }
      e0.x += exc.x; e0.y += exc.y; e1.x += exc.x; e1.y += exc.y;
      e2.x += exc.x; e2.y += exc.y; e3.x += exc.x; e3.y += exc.y;
      i0.x += exc.z; i0.y += exc.w; i1.x += exc.z; i1.y += exc.w;
      i2v.x += exc.z; i2v.y += exc.w; i3.x += exc.z; i3.y += exc.w;
      S.scanE[4 * tid] = e0; S.scanE[4 * tid + 1] = e1;
      S.scanE[4 * tid + 2] = e2; S.scanE[4 * tid + 3] = e3;
      S.scanI[4 * tid] = i0; S.scanI[4 * tid + 1] = i1;
      S.scanI[4 * tid + 2] = i2v; S.scanI[4 * tid + 3] = i3;
      __syncthreads();

      float nv[4] = {0.f, 0.f, 0.f, 0.f};
      float psum = 0.0f;
      if (tid < 240) {
        float2 TE = S.scanE[NSRC], TI = S.scanI[NSRC];
        float pr[4];
        #pragma unroll
        for (int c = 0; c < 4; ++c) {
          float2 AE = S.scanE[cE[c]], AI = S.scanI[cI[c]];
          float dot = fm[c] * AE.x + fp[c] * (TE.y - AE.y)
                    - fm[c] * AI.x - fp[c] * (TI.y - AI.y);
          float pre = y_own[c] + dN * dot;
          pr[c] = pre;
          if (t < NWARM) {
            nv[c] = fmaxf(pre + hd[c], 0.0f);
            psum += nv[c];
          }
        }
        if (t == NWARM) {
          ast(&BSP[2 * tid],
              (u64)__float_as_uint(pr[0]) | ((u64)__float_as_uint(pr[1]) << 32));
          ast(&BSP[2 * tid + 1],
              (u64)__float_as_uint(pr[2]) | ((u64)__float_as_uint(pr[3]) << 32));
        }
      }
      if (t < NWARM) {
        #pragma unroll
        for (int off = 32; off >= 1; off >>= 1) psum += __shfl_xor(psum, off);
        if (lane == 0) S.ssw[wvid] = psum;
        __syncthreads();
        float s2 = S.ssw[0] + S.ssw[1] + S.ssw[2] + S.ssw[3];
        float inv = (s2 > 0.0f) ? 1.0f / s2 : 1.0f;
        if (tid < 240) {
          #pragma unroll
          for (int c = 0; c < 4; ++c) {
            y_own[c] = nv[c] * inv;
            S.yl[4 * tid + c] = y_own[c];
          }
        }
      }
      __syncthreads();
    }
    if (tid == 0)
      __hip_atomic_store(DN, ((u64)TAG_DN << 32) | 1u, __ATOMIC_RELEASE,
                         __HIP_MEMORY_SCOPE_AGENT);
    return;
  }

  // -------------- batch prefetch (before prep/sleep; loads hide there) -----
  const int r_ld = tid >> 4, c4_ld = (tid & 15) * 4;
  float4 f4 = *(const float4*)(inp + ((size_t)(blockIdx.x - 1) * 16 + r_ld) * 64 + c4_ld);
  float eL = 0.f, ivL = 0.f;
  if (tid < 64) { eL = enh[tid]; ivL = inh[tid]; }
  const float cjA0 = ident[64 + tid];
  const float cjB0 = ident[64 + 256 + tid];
  const float cjA1 = ident[64 + 512 + tid];
  const bool okB1 = (768 + tid) < NJ;
  const float cjB1 = okB1 ? ident[64 + 768 + tid] : 0.0f;
  // pin the prefetch live so the load issues before prep/sleep
  asm volatile("" :: "v"(f4.x), "v"(f4.y), "v"(f4.z), "v"(f4.w));

  if (blockIdx.x <= 30) {
    // ---------------- prep prologue (blocks 1..30; no sleep) ----------------
    const int g = (int)(blockIdx.x - 1) * 256 + tid;  // 0..7679
    const int c8 = g & 7;
    if (g < NSRC * 8) {
      int m = g >> 3;
      float myE = enh[128 + m], myI = inh[128 + m];
      int re = 0, ri = 0;
      for (int i = 112 * c8; i < 112 * c8 + 112; ++i) {
        float ev = enh[128 + i], iv = inh[128 + i];
        re += (ev < myE || (ev == myE && i < m)) ? 1 : 0;
        ri += (iv < myI || (iv == myI && i < m)) ? 1 : 0;
      }
      int p = re | (ri << 16);
      p += __shfl_xor(p, 1); p += __shfl_xor(p, 2); p += __shfl_xor(p, 4);
      if (c8 == 0) ast(&RK[m], ((u64)TAG_RK << 32) | (u32)p);
    }
    {
      int j = g >> 3;
      float cj = ident[64 + j];
      int ce = 0, ci = 0;
      for (int i = 112 * c8; i < 112 * c8 + 112; ++i) {
        ce += (enh[128 + i] <= cj) ? 1 : 0;
        ci += (inh[128 + i] <= cj) ? 1 : 0;
      }
      int p = ce | (ci << 16);
      p += __shfl_xor(p, 1); p += __shfl_xor(p, 2); p += __shfl_xor(p, 4);
      if (c8 == 0) ast(&CT[j], ((u64)TAG_CT << 32) | (u32)p);
    }
    {
      int j = g >> 3;
      float cj = ident[64 + j];
      float h = 0.0f;
      for (int k = 8 * c8; k < 8 * c8 + 8; ++k)
        h += expf(-bb * fabsf(enh[k] - cj)) - expf(-bb * fabsf(inh[k] - cj));
      h += __shfl_xor(h, 1); h += __shfl_xor(h, 2); h += __shfl_xor(h, 4);
      if (c8 == 0)
        ast(&HD[j], ((u64)TAG_HD << 32) |
                    (u64)__float_as_uint(dN * h * (1.0f / 1024.0f)));
    }
  } else {
    // stagger batch start: let prep + scan launch on a quiet GPU.
    // 4..11 iters x ~3.4 us = 13.6..37.4 us; batch needs <=25 us of the scan's
    // ~85 us window, so worst case finishes ~60 us < DN. Perf hint only.
    const int nsleep = 4 + (int)(blockIdx.x & 7);
    for (int i = 0; i < nsleep; ++i) __builtin_amdgcn_s_sleep(127);
  }

  // ---------------- batch (blocks 1..1023; block 1 also does tile 1023) ----
  BatSm& Bm = *(BatSm*)smraw;
  const int colg = tid & 63;
  const int rowg = tid >> 6;             // wave id == row group (4 rows each)
  const int nsub = (blockIdx.x == 1) ? 2 : 1;

  const float fpA0 = expf(bb * cjA0), fmA0 = expf(-bb * cjA0);
  const float fpB0 = expf(bb * cjB0), fmB0 = expf(-bb * cjB0);
  const float fpA1 = expf(bb * cjA1), fmA1 = expf(-bb * cjA1);
  const float fpB1 = expf(bb * cjB1), fmB1 = expf(-bb * cjB1);

  for (int sub = 0; sub < nsub; ++sub) {
    const int tile = (sub == 0) ? (int)blockIdx.x - 1 : 1023;
    const size_t rowbase = (size_t)tile * 16;
    if (sub == 1)
      f4 = *(const float4*)(inp + (rowbase + r_ld) * 64 + c4_ld);

    // stage input tile (At reads in prior sub finished before DN barrier)
    Bm.At[c4_ld + 0][r_ld] = f4.x; Bm.At[c4_ld + 1][r_ld] = f4.y;
    Bm.At[c4_ld + 2][r_ld] = f4.z; Bm.At[c4_ld + 3][r_ld] = f4.w;
    if (sub == 0 && tid < 64) {
      Bm.Ek4[tid] = make_float4(expf(bb * eL), expf(-bb * eL),
                                expf(bb * ivL), expf(-bb * ivL));
      Bm.Ei2[tid] = make_float2(eL, ivL);
    }

    float acc0[4][8], acc1[4][8];        // both chunks live: 64 regs
    #pragma unroll
    for (int r = 0; r < 4; ++r)
      #pragma unroll
      for (int c = 0; c < 8; ++c) { acc0[r][c] = 0.0f; acc1[r][c] = 0.0f; }

    // Weights recomputed from the separable form:
    // exp(-b|e-c|) = (e>=c) ? e^{-be} e^{+bc} : e^{+be} e^{-bc}
    {  // ---- chunk 0: cols 0..511 ----
      #pragma unroll 1
      for (int s = 0; s < 4; ++s) {
        __syncthreads();
        #pragma unroll 4
        for (int e = 0; e < 16; ++e) {
          int k = 16 * s + e;
          float4 E = Bm.Ek4[k];
          float2 ei = Bm.Ei2[k];
          Bm.Wl[e][tid] = dN * (((ei.x >= cjA0) ? E.y * fpA0 : E.x * fmA0)
                              - ((ei.y >= cjA0) ? E.w * fpA0 : E.z * fmA0));
          Bm.Wl[e][tid + 256] = dN * (((ei.x >= cjB0) ? E.y * fpB0 : E.x * fmB0)
                                    - ((ei.y >= cjB0) ? E.w * fpB0 : E.z * fmB0));
        }
        __syncthreads();
        #pragma unroll
        for (int kk = 0; kk < 16; ++kk) {
          float4 av = *(const float4*)&Bm.At[16 * s + kk][rowg * 4];  // bcast
          float4 w0 = *(const float4*)&Bm.Wl[kk][colg * 4];
          float4 w1 = *(const float4*)&Bm.Wl[kk][256 + colg * 4];
          float a_[4] = {av.x, av.y, av.z, av.w};
          float w_[8] = {w0.x, w0.y, w0.z, w0.w, w1.x, w1.y, w1.z, w1.w};
          #pragma unroll
          for (int r = 0; r < 4; ++r)
            #pragma unroll
            for (int c = 0; c < 8; ++c)
              acc0[r][c] = fmaf(a_[r], w_[c], acc0[r][c]);
        }
      }
    }
    {  // ---- chunk 1: cols 512..959 (tail guarded) ----
      #pragma unroll 1
      for (int s = 0; s < 4; ++s) {
        __syncthreads();
        #pragma unroll 4
        for (int e = 0; e < 16; ++e) {
          int k = 16 * s + e;
          float4 E = Bm.Ek4[k];
          float2 ei = Bm.Ei2[k];
          Bm.Wl[e][tid] = dN * (((ei.x >= cjA1) ? E.y * fpA1 : E.x * fmA1)
                              - ((ei.y >= cjA1) ? E.w * fpA1 : E.z * fmA1));
          float wB = 0.0f;
          if (okB1)
            wB = dN * (((ei.x >= cjB1) ? E.y * fpB1 : E.x * fmB1)
                     - ((ei.y >= cjB1) ? E.w * fpB1 : E.z * fmB1));
          Bm.Wl[e][tid + 256] = wB;
        }
        __syncthreads();
        #pragma unroll
        for (int kk = 0; kk < 16; ++kk) {
          float4 av = *(const float4*)&Bm.At[16 * s + kk][rowg * 4];  // bcast
          float4 w0 = *(const float4*)&Bm.Wl[kk][colg * 4];
          float4 w1 = *(const float4*)&Bm.Wl[kk][256 + colg * 4];
          float a_[4] = {av.x, av.y, av.z, av.w};
          float w_[8] = {w0.x, w0.y, w0.z, w0.w, w1.x, w1.y, w1.z, w1.w};
          #pragma unroll
          for (int r = 0; r < 4; ++r)
            #pragma unroll
            for (int c = 0; c < 8; ++c)
              acc1[r][c] = fmaf(a_[r], w_[c], acc1[r][c]);
        }
      }
    }

    // ---- the ONE wait: base published by scan at t==NWARM ----
    if (tid == 0) {
      u64 v = ald(DN);
      while ((u32)(v >> 32) != TAG_DN) { __builtin_amdgcn_s_sleep(32); v = ald(DN); }
      (void)__hip_atomic_load(DN, __ATOMIC_ACQUIRE, __HIP_MEMORY_SCOPE_AGENT);
    }
    __syncthreads();   // all Wl reads done -> bch (union) may overwrite
    if (tid < 240) {
      u64 w0 = ald(&BSP[2 * tid]);
      u64 w1 = ald(&BSP[2 * tid + 1]);
      Bm.bch[4 * tid + 0] = __uint_as_float((u32)w0);
      Bm.bch[4 * tid + 1] = __uint_as_float((u32)(w0 >> 32));
      Bm.bch[4 * tid + 2] = __uint_as_float((u32)w1);
      Bm.bch[4 * tid + 3] = __uint_as_float((u32)(w1 >> 32));
    }
    __syncthreads();

    // ---- epilogue: relu row-sums over both chunks, normalize + store ----
    float rs[4] = {0.f, 0.f, 0.f, 0.f};
    #pragma unroll
    for (int c = 0; c < 8; ++c) {
      int cl = (c < 4) ? (colg * 4 + c) : (256 + colg * 4 + (c - 4));
      float bv0 = Bm.bch[cl];
      int j1 = 512 + cl;
      float bv1 = (j1 < NJ) ? Bm.bch[j1] : -1.0e30f;  // acc1 is 0 there
      #pragma unroll
      for (int r = 0; r < 4; ++r) {
        rs[r] += fmaxf(acc0[r][c] + bv0, 0.0f);
        rs[r] += fmaxf(acc1[r][c] + bv1, 0.0f);
      }
    }
    #pragma unroll
    for (int r = 0; r < 4; ++r) {
      float v = rs[r];
      #pragma unroll
      for (int off = 32; off >= 1; off >>= 1) v += __shfl_xor(v, off);
      rs[r] = v;
    }
    if (colg < 16) {
      #pragma unroll
      for (int r = 0; r < 4; ++r) {
        float inv = (rs[r] > 0.0f) ? 1.0f / rs[r] : 1.0f;
        float* op = out + (rowbase + rowg * 4 + r) * 64 + colg * 4;
        float4 o;
        o.x = fmaxf(acc0[r][0] + Bm.bch[colg * 4 + 0], 0.0f) * inv;
        o.y = fmaxf(acc0[r][1] + Bm.bch[colg * 4 + 1], 0.0f) * inv;
        o.z = fmaxf(acc0[r][2] + Bm.bch[colg * 4 + 2], 0.0f) * inv;
        o.w = fmaxf(acc0[r][3] + Bm.bch[colg * 4 + 3], 0.0f) * inv;
        *(float4*)op = o;
      }
    }
  }
}

extern "C" void kernel_launch(void* const* d_in, const int* in_sizes, int n_in,
                              void* d_out, int out_size, void* d_ws, size_t ws_size,
                              hipStream_t stream) {
  const float* inp   = (const float*)d_in[0];
  const float* ident = (const float*)d_in[1];
  const float* enh   = (const float*)d_in[2];
  const float* inh   = (const float*)d_in[3];
  const float* beta  = (const float*)d_in[4];
  const float* delta = (const float*)d_in[5];

  hipLaunchKernelGGL(grn_all, dim3(1024), dim3(256), 0, stream,
                     inp, ident, enh, inh, beta, delta, d_ws, (float*)d_out);
}

// Round 6
// 171.893 us; speedup vs baseline: 1.1596x; 1.1596x over previous
//
#include <hip/hip_runtime.h>
#include <math.h>

#define NJ 960           // tail columns (global 64..1023)
#define NSRC 896         // tail sources (global 128..1023)
#define NWARM 25

typedef unsigned long long u64;
typedef unsigned int u32;

// ws layout (u64 indices):
//   RK[896]  : tag | (rE | rI<<16)
//   CT[960]  : tag | (cntE | cntI<<16)
//   HD[960]  : tag | float bits of hd[j]
//   BSP[480] : packed pair (base[2w] | base[2w+1]<<32) — ordered by DN rel/acq
//   DN[1]    : tag — DONE flag (release-published by scan)
#define RK_O 0u
#define CT_O 896u
#define HD_O 1856u
#define BSP_O 2816u
#define DN_O 3776u

#define TAG_RK 0x524B0001u
#define TAG_CT 0x43540001u
#define TAG_HD 0x48440001u
#define TAG_DN 0x444E0001u

__device__ __forceinline__ void ast(u64* p, u64 v) {
  __hip_atomic_store(p, v, __ATOMIC_RELAXED, __HIP_MEMORY_SCOPE_AGENT);
}
__device__ __forceinline__ u64 ald(const u64* p) {
  return __hip_atomic_load(p, __ATOMIC_RELAXED, __HIP_MEMORY_SCOPE_AGENT);
}
__device__ __forceinline__ u32 poll32(const u64* p, u32 tag) {
  u64 v = ald(p);
  while ((u32)(v >> 32) != tag) { __builtin_amdgcn_s_sleep(1); v = ald(p); }
  return (u32)v;
}

struct ScanSm {
  float yl[NJ];
  float2 scanE[1024];
  float2 scanI[1024];
  float4 wtot[4];
  float ssw[4];
};
struct BatSm {
  float At[64][16];     // transposed input tile (16 rows); reads wave-broadcast
  union {
    float Wl[16][512];  // weight tile (live during MMA)
    float bch[NJ];      // base bias (live after DN; Wl dead) — union saves 4 KB
  };
  float4 Ek4[64];       // {e^{+be}, e^{-be}, e^{+bi}, e^{-bi}} per head source
  float2 Ei2[64];       // raw {e_k, i_k}
};
// BatSm = 4096 + 32768 + 1024 + 512 = 38400 B -> 4 blocks/CU -> 1024 slots =
// whole grid resident. ScanSm (20.3 KB) unions into the same smraw; block 0
// reuses it as BatSm after the scan (ScanSm dead past the final barrier).

// Fused kernel, grid 1024:
//   block 0      : warmup scan at s_setprio(1), then tile 1023 post-DN
//   blocks 1..30 : prep (ranks/counts/hd) at setprio(1), then batch tile b-1
//   blocks 31..1023: batch tile b-1
// setprio: each SIMD on the scan's CU hosts 1 scan wave + 3 batch waves; the
// scan is a 26-iter latency chain and loses issue slots to the batch storm
// (rounds 4/5: ~115-120 us effective scan). Priority 1 on scan/prep waves
// restores near-solo progress; batch fills slack slots. Perf hint only —
// dependency graph (scan<-prep, batch<-scan) unchanged, deadlock-free since
// blocks 0..30 are first-dispatched and always resident.
__global__ __launch_bounds__(256, 2) void grn_all(
    const float* __restrict__ inp, const float* __restrict__ ident,
    const float* __restrict__ enh, const float* __restrict__ inh,
    const float* __restrict__ beta, const float* __restrict__ delta,
    void* __restrict__ wsv, float* __restrict__ out) {
  __shared__ __align__(16) char smraw[(sizeof(BatSm) > sizeof(ScanSm))
                                          ? sizeof(BatSm) : sizeof(ScanSm)];
  u64* RK = (u64*)wsv + RK_O;
  u64* CT = (u64*)wsv + CT_O;
  u64* HD = (u64*)wsv + HD_O;
  u64* BSP = (u64*)wsv + BSP_O;
  u64* DN = (u64*)wsv + DN_O;

  const int tid = threadIdx.x;
  const float bb = beta[0];
  const float dN = delta[0] / 1024.0f;

  int tile;
  if (blockIdx.x == 0) {
    // ---------------- scan block (proven code; now at prio 1) ----------------
    __builtin_amdgcn_s_setprio(1);
    ScanSm& S = *(ScanSm*)smraw;
    const int lane = tid & 63, wvid = tid >> 6;

    int rE[4], rI[4];
    if (tid < 224) {
      #pragma unroll
      for (int s = 0; s < 4; ++s) {
        u32 v = poll32(&RK[4 * tid + s], TAG_RK);
        rE[s] = v & 0xFFFF; rI[s] = v >> 16;
      }
    }
    int cE[4], cI[4];
    float hd[4], fm[4], fp[4];
    if (tid < 240) {
      #pragma unroll
      for (int c = 0; c < 4; ++c) {
        u32 v = poll32(&CT[4 * tid + c], TAG_CT);
        cE[c] = v & 0xFFFF; cI[c] = v >> 16;
        hd[c] = __uint_as_float(poll32(&HD[4 * tid + c], TAG_HD));
        float cj = ident[64 + 4 * tid + c];
        fm[c] = expf(-bb * cj); fp[c] = expf(bb * cj);
      }
    }
    float EP[4], EN[4], IP[4], IN2[4];
    if (tid < 224) {
      #pragma unroll
      for (int s = 0; s < 4; ++s) {
        float e = enh[128 + 4 * tid + s], i2 = inh[128 + 4 * tid + s];
        EP[s] = expf(bb * e);  EN[s] = expf(-bb * e);
        IP[s] = expf(bb * i2); IN2[s] = expf(-bb * i2);
      }
    }
    float y_own[4] = {1.0f / 1024.0f, 1.0f / 1024.0f, 1.0f / 1024.0f, 1.0f / 1024.0f};
    if (tid < 240) {
      #pragma unroll
      for (int c = 0; c < 4; ++c) S.yl[4 * tid + c] = 1.0f / 1024.0f;
    }
    __syncthreads();

    for (int t = 0; t <= NWARM; ++t) {
      if (tid == 0) {
        S.scanE[0] = make_float2(0.f, 0.f);
        S.scanI[0] = make_float2(0.f, 0.f);
      }
      if (tid >= 224) {
        #pragma unroll
        for (int c = 0; c < 4; ++c) {
          int p = 4 * tid + c;
          if (p > NSRC) {
            S.scanE[p] = make_float2(0.f, 0.f);
            S.scanI[p] = make_float2(0.f, 0.f);
          }
        }
      }
      if (tid < 224) {
        #pragma unroll
        for (int s = 0; s < 4; ++s) {
          float ym = S.yl[64 + 4 * tid + s];
          S.scanE[rE[s] + 1] = make_float2(ym * EP[s], ym * EN[s]);
          S.scanI[rI[s] + 1] = make_float2(ym * IP[s], ym * IN2[s]);
        }
      }
      __syncthreads();

      float2 e0 = S.scanE[4 * tid], e1 = S.scanE[4 * tid + 1],
             e2 = S.scanE[4 * tid + 2], e3 = S.scanE[4 * tid + 3];
      float2 i0 = S.scanI[4 * tid], i1 = S.scanI[4 * tid + 1],
             i2v = S.scanI[4 * tid + 2], i3 = S.scanI[4 * tid + 3];
      e1.x += e0.x; e1.y += e0.y; e2.x += e1.x; e2.y += e1.y; e3.x += e2.x; e3.y += e2.y;
      i1.x += i0.x; i1.y += i0.y; i2v.x += i1.x; i2v.y += i1.y; i3.x += i2v.x; i3.y += i2v.y;
      float4 tot = make_float4(e3.x, e3.y, i3.x, i3.y);
      float4 inc = tot;
      #pragma unroll
      for (int off = 1; off < 64; off <<= 1) {
        float ox = __shfl_up(inc.x, off, 64);
        float oy = __shfl_up(inc.y, off, 64);
        float oz = __shfl_up(inc.z, off, 64);
        float ow = __shfl_up(inc.w, off, 64);
        if (lane >= off) { inc.x += ox; inc.y += oy; inc.z += oz; inc.w += ow; }
      }
      if (lane == 63) S.wtot[wvid] = inc;
      __syncthreads();
      float4 exc = make_float4(inc.x - tot.x, inc.y - tot.y,
                               inc.z - tot.z, inc.w - tot.w);
      #pragma unroll
      for (int w = 0; w < 3; ++w)
        if (w < wvid) {
          float4 p = S.wtot[w];
          exc.x += p.x; exc.y += p.y; exc.z += p.z; exc.w += p.w;
        }
      e0.x += exc.x; e0.y += exc.y; e1.x += exc.x; e1.y += exc.y;
      e2.x += exc.x; e2.y += exc.y; e3.x += exc.x; e3.y += exc.y;
      i0.x += exc.z; i0.y += exc.w; i1.x += exc.z; i1.y += exc.w;
      i2v.x += exc.z; i2v.y += exc.w; i3.x += exc.z; i3.y += exc.w;
      S.scanE[4 * tid] = e0; S.scanE[4 * tid + 1] = e1;
      S.scanE[4 * tid + 2] = e2; S.scanE[4 * tid + 3] = e3;
      S.scanI[4 * tid] = i0; S.scanI[4 * tid + 1] = i1;
      S.scanI[4 * tid + 2] = i2v; S.scanI[4 * tid + 3] = i3;
      __syncthreads();

      float nv[4] = {0.f, 0.f, 0.f, 0.f};
      float psum = 0.0f;
      if (tid < 240) {
        float2 TE = S.scanE[NSRC], TI = S.scanI[NSRC];
        float pr[4];
        #pragma unroll
        for (int c = 0; c < 4; ++c) {
          float2 AE = S.scanE[cE[c]], AI = S.scanI[cI[c]];
          float dot = fm[c] * AE.x + fp[c] * (TE.y - AE.y)
                    - fm[c] * AI.x - fp[c] * (TI.y - AI.y);
          float pre = y_own[c] + dN * dot;
          pr[c] = pre;
          if (t < NWARM) {
            nv[c] = fmaxf(pre + hd[c], 0.0f);
            psum += nv[c];
          }
        }
        if (t == NWARM) {
          ast(&BSP[2 * tid],
              (u64)__float_as_uint(pr[0]) | ((u64)__float_as_uint(pr[1]) << 32));
          ast(&BSP[2 * tid + 1],
              (u64)__float_as_uint(pr[2]) | ((u64)__float_as_uint(pr[3]) << 32));
        }
      }
      if (t < NWARM) {
        #pragma unroll
        for (int off = 32; off >= 1; off >>= 1) psum += __shfl_xor(psum, off);
        if (lane == 0) S.ssw[wvid] = psum;
        __syncthreads();
        float s2 = S.ssw[0] + S.ssw[1] + S.ssw[2] + S.ssw[3];
        float inv = (s2 > 0.0f) ? 1.0f / s2 : 1.0f;
        if (tid < 240) {
          #pragma unroll
          for (int c = 0; c < 4; ++c) {
            y_own[c] = nv[c] * inv;
            S.yl[4 * tid + c] = y_own[c];
          }
        }
      }
      __syncthreads();
    }
    if (tid == 0)
      __hip_atomic_store(DN, ((u64)TAG_DN << 32) | 1u, __ATOMIC_RELEASE,
                         __HIP_MEMORY_SCOPE_AGENT);
    __builtin_amdgcn_s_setprio(0);
    tile = 1023;          // scan's CU is idle post-DN; take the leftover tile
  } else {
    tile = (int)blockIdx.x - 1;
    if (blockIdx.x <= 30) {
      // ------------- prep prologue (blocks 1..30; prio 1 vs the storm) ------
      __builtin_amdgcn_s_setprio(1);
      const int g = (int)(blockIdx.x - 1) * 256 + tid;  // 0..7679
      const int c8 = g & 7;
      if (g < NSRC * 8) {
        int m = g >> 3;
        float myE = enh[128 + m], myI = inh[128 + m];
        int re = 0, ri = 0;
        for (int i = 112 * c8; i < 112 * c8 + 112; ++i) {
          float ev = enh[128 + i], iv = inh[128 + i];
          re += (ev < myE || (ev == myE && i < m)) ? 1 : 0;
          ri += (iv < myI || (iv == myI && i < m)) ? 1 : 0;
        }
        int p = re | (ri << 16);
        p += __shfl_xor(p, 1); p += __shfl_xor(p, 2); p += __shfl_xor(p, 4);
        if (c8 == 0) ast(&RK[m], ((u64)TAG_RK << 32) | (u32)p);
      }
      {
        int j = g >> 3;
        float cj = ident[64 + j];
        int ce = 0, ci = 0;
        for (int i = 112 * c8; i < 112 * c8 + 112; ++i) {
          ce += (enh[128 + i] <= cj) ? 1 : 0;
          ci += (inh[128 + i] <= cj) ? 1 : 0;
        }
        int p = ce | (ci << 16);
        p += __shfl_xor(p, 1); p += __shfl_xor(p, 2); p += __shfl_xor(p, 4);
        if (c8 == 0) ast(&CT[j], ((u64)TAG_CT << 32) | (u32)p);
      }
      {
        int j = g >> 3;
        float cj = ident[64 + j];
        float h = 0.0f;
        for (int k = 8 * c8; k < 8 * c8 + 8; ++k)
          h += expf(-bb * fabsf(enh[k] - cj)) - expf(-bb * fabsf(inh[k] - cj));
        h += __shfl_xor(h, 1); h += __shfl_xor(h, 2); h += __shfl_xor(h, 4);
        if (c8 == 0)
          ast(&HD[j], ((u64)TAG_HD << 32) |
                      (u64)__float_as_uint(dN * h * (1.0f / 1024.0f)));
      }
      __builtin_amdgcn_s_setprio(0);
    }
  }

  // ---------------- batch (all 1024 blocks; one 16-row tile each) ----------
  BatSm& Bm = *(BatSm*)smraw;
  const int colg = tid & 63;
  const int rowg = tid >> 6;             // wave id == row group (4 rows each)
  const size_t rowbase = (size_t)tile * 16;

  const int r_ld = tid >> 4, c4_ld = (tid & 15) * 4;
  float4 f4 = *(const float4*)(inp + (rowbase + r_ld) * 64 + c4_ld);
  const float cjA0 = ident[64 + tid];
  const float cjB0 = ident[64 + 256 + tid];
  const float cjA1 = ident[64 + 512 + tid];
  const bool okB1 = (768 + tid) < NJ;
  const float cjB1 = okB1 ? ident[64 + 768 + tid] : 0.0f;
  const float fpA0 = expf(bb * cjA0), fmA0 = expf(-bb * cjA0);
  const float fpB0 = expf(bb * cjB0), fmB0 = expf(-bb * cjB0);
  const float fpA1 = expf(bb * cjA1), fmA1 = expf(-bb * cjA1);
  const float fpB1 = expf(bb * cjB1), fmB1 = expf(-bb * cjB1);

  // block 0 reuses smraw: ScanSm fully dead past the scan's final barrier.
  if (blockIdx.x == 0) __syncthreads();

  Bm.At[c4_ld + 0][r_ld] = f4.x; Bm.At[c4_ld + 1][r_ld] = f4.y;
  Bm.At[c4_ld + 2][r_ld] = f4.z; Bm.At[c4_ld + 3][r_ld] = f4.w;
  if (tid < 64) {
    float e = enh[tid], iv = inh[tid];
    Bm.Ek4[tid] = make_float4(expf(bb * e), expf(-bb * e),
                              expf(bb * iv), expf(-bb * iv));
    Bm.Ei2[tid] = make_float2(e, iv);
  }

  float acc0[4][8], acc1[4][8];          // both chunks live: 64 regs
  #pragma unroll
  for (int r = 0; r < 4; ++r)
    #pragma unroll
    for (int c = 0; c < 8; ++c) { acc0[r][c] = 0.0f; acc1[r][c] = 0.0f; }

  // Weights recomputed from the separable form:
  // exp(-b|e-c|) = (e>=c) ? e^{-be} e^{+bc} : e^{+be} e^{-bc}
  {  // ---- chunk 0: cols 0..511 ----
    #pragma unroll 1
    for (int s = 0; s < 4; ++s) {
      __syncthreads();
      #pragma unroll 4
      for (int e = 0; e < 16; ++e) {
        int k = 16 * s + e;
        float4 E = Bm.Ek4[k];
        float2 ei = Bm.Ei2[k];
        Bm.Wl[e][tid] = dN * (((ei.x >= cjA0) ? E.y * fpA0 : E.x * fmA0)
                            - ((ei.y >= cjA0) ? E.w * fpA0 : E.z * fmA0));
        Bm.Wl[e][tid + 256] = dN * (((ei.x >= cjB0) ? E.y * fpB0 : E.x * fmB0)
                                  - ((ei.y >= cjB0) ? E.w * fpB0 : E.z * fmB0));
      }
      __syncthreads();
      #pragma unroll
      for (int kk = 0; kk < 16; ++kk) {
        float4 av = *(const float4*)&Bm.At[16 * s + kk][rowg * 4];  // bcast
        float4 w0 = *(const float4*)&Bm.Wl[kk][colg * 4];
        float4 w1 = *(const float4*)&Bm.Wl[kk][256 + colg * 4];
        float a_[4] = {av.x, av.y, av.z, av.w};
        float w_[8] = {w0.x, w0.y, w0.z, w0.w, w1.x, w1.y, w1.z, w1.w};
        #pragma unroll
        for (int r = 0; r < 4; ++r)
          #pragma unroll
          for (int c = 0; c < 8; ++c)
            acc0[r][c] = fmaf(a_[r], w_[c], acc0[r][c]);
      }
    }
  }
  {  // ---- chunk 1: cols 512..959 (tail guarded) ----
    #pragma unroll 1
    for (int s = 0; s < 4; ++s) {
      __syncthreads();
      #pragma unroll 4
      for (int e = 0; e < 16; ++e) {
        int k = 16 * s + e;
        float4 E = Bm.Ek4[k];
        float2 ei = Bm.Ei2[k];
        Bm.Wl[e][tid] = dN * (((ei.x >= cjA1) ? E.y * fpA1 : E.x * fmA1)
                            - ((ei.y >= cjA1) ? E.w * fpA1 : E.z * fmA1));
        float wB = 0.0f;
        if (okB1)
          wB = dN * (((ei.x >= cjB1) ? E.y * fpB1 : E.x * fmB1)
                   - ((ei.y >= cjB1) ? E.w * fpB1 : E.z * fmB1));
        Bm.Wl[e][tid + 256] = wB;
      }
      __syncthreads();
      #pragma unroll
      for (int kk = 0; kk < 16; ++kk) {
        float4 av = *(const float4*)&Bm.At[16 * s + kk][rowg * 4];  // bcast
        float4 w0 = *(const float4*)&Bm.Wl[kk][colg * 4];
        float4 w1 = *(const float4*)&Bm.Wl[kk][256 + colg * 4];
        float a_[4] = {av.x, av.y, av.z, av.w};
        float w_[8] = {w0.x, w0.y, w0.z, w0.w, w1.x, w1.y, w1.z, w1.w};
        #pragma unroll
        for (int r = 0; r < 4; ++r)
          #pragma unroll
          for (int c = 0; c < 8; ++c)
            acc1[r][c] = fmaf(a_[r], w_[c], acc1[r][c]);
      }
    }
  }

  // ---- the ONE wait: base published by scan at t==NWARM ----
  if (tid == 0) {
    u64 v = ald(DN);
    while ((u32)(v >> 32) != TAG_DN) { __builtin_amdgcn_s_sleep(32); v = ald(DN); }
    (void)__hip_atomic_load(DN, __ATOMIC_ACQUIRE, __HIP_MEMORY_SCOPE_AGENT);
  }
  __syncthreads();   // all Wl reads done -> bch (union) may overwrite
  if (tid < 240) {
    u64 w0 = ald(&BSP[2 * tid]);
    u64 w1 = ald(&BSP[2 * tid + 1]);
    Bm.bch[4 * tid + 0] = __uint_as_float((u32)w0);
    Bm.bch[4 * tid + 1] = __uint_as_float((u32)(w0 >> 32));
    Bm.bch[4 * tid + 2] = __uint_as_float((u32)w1);
    Bm.bch[4 * tid + 3] = __uint_as_float((u32)(w1 >> 32));
  }
  __syncthreads();

  // ---- epilogue: relu row-sums over both chunks, normalize + store ----
  float rs[4] = {0.f, 0.f, 0.f, 0.f};
  #pragma unroll
  for (int c = 0; c < 8; ++c) {
    int cl = (c < 4) ? (colg * 4 + c) : (256 + colg * 4 + (c - 4));
    float bv0 = Bm.bch[cl];
    int j1 = 512 + cl;
    float bv1 = (j1 < NJ) ? Bm.bch[j1] : -1.0e30f;  // acc1 is 0 there
    #pragma unroll
    for (int r = 0; r < 4; ++r) {
      rs[r] += fmaxf(acc0[r][c] + bv0, 0.0f);
      rs[r] += fmaxf(acc1[r][c] + bv1, 0.0f);
    }
  }
  #pragma unroll
  for (int r = 0; r < 4; ++r) {
    float v = rs[r];
    #pragma unroll
    for (int off = 32; off >= 1; off >>= 1) v += __shfl_xor(v, off);
    rs[r] = v;
  }
  if (colg < 16) {
    #pragma unroll
    for (int r = 0; r < 4; ++r) {
      float inv = (rs[r] > 0.0f) ? 1.0f / rs[r] : 1.0f;
      float* op = out + (rowbase + rowg * 4 + r) * 64 + colg * 4;
      float4 o;
      o.x = fmaxf(acc0[r][0] + Bm.bch[colg * 4 + 0], 0.0f) * inv;
      o.y = fmaxf(acc0[r][1] + Bm.bch[colg * 4 + 1], 0.0f) * inv;
      o.z = fmaxf(acc0[r][2] + Bm.bch[colg * 4 + 2], 0.0f) * inv;
      o.w = fmaxf(acc0[r][3] + Bm.bch[colg * 4 + 3], 0.0f) * inv;
      *(float4*)op = o;
    }
  }
}

extern "C" void kernel_launch(void* const* d_in, const int* in_sizes, int n_in,
                              void* d_out, int out_size, void* d_ws, size_t ws_size,
                              hipStream_t stream) {
  const float* inp   = (const float*)d_in[0];
  const float* ident = (const float*)d_in[1];
  const float* enh   = (const float*)d_in[2];
  const float* inh   = (const float*)d_in[3];
  const float* beta  = (const float*)d_in[4];
  const float* delta = (const float*)d_in[5];

  hipLaunchKernelGGL(grn_all, dim3(1024), dim3(256), 0, stream,
                     inp, ident, enh, inh, beta, delta, d_ws, (float*)d_out);
}

// Round 7
// 160.807 us; speedup vs baseline: 1.2396x; 1.0689x over previous
//
#include <hip/hip_runtime.h>
#include <math.h>

#define NJ 960           // tail columns (global 64..1023)
#define NSRC 896         // tail sources (global 128..1023)
#define NWARM 25

typedef unsigned long long u64;
typedef unsigned int u32;

// ws layout:
//   u64 idx: RK[896] tag|(rE|rI<<16), CT[960] tag|(cntE|cntI<<16),
//            HD[960] tag|float(hd[j])
//   float idx 8192: base[960] (plain floats; K1->K2 ordering via kernel
//   boundary — exact round-0 protocol, proven)
#define RK_O 0u
#define CT_O 896u
#define HD_O 1856u
#define BASE_F 8192u

#define TAG_RK 0x524B0001u
#define TAG_CT 0x43540001u
#define TAG_HD 0x48440001u

__device__ __forceinline__ void ast(u64* p, u64 v) {
  __hip_atomic_store(p, v, __ATOMIC_RELAXED, __HIP_MEMORY_SCOPE_AGENT);
}
__device__ __forceinline__ u64 ald(const u64* p) {
  return __hip_atomic_load(p, __ATOMIC_RELAXED, __HIP_MEMORY_SCOPE_AGENT);
}
__device__ __forceinline__ u32 poll32(const u64* p, u32 tag) {
  u64 v = ald(p);
  while ((u32)(v >> 32) != tag) { __builtin_amdgcn_s_sleep(1); v = ald(p); }
  return (u32)v;
}

// K1: block 0 = single-block scan warmup; blocks 1..30 = prep (ranks/counts/hd)
// publishing via epoch tags. Round-0 proven code; Wk table (part D) removed —
// K2 recomputes weights in-LDS instead.
__global__ __launch_bounds__(256) void front_k(const float* __restrict__ ident,
                                               const float* __restrict__ enh,
                                               const float* __restrict__ inh,
                                               const float* __restrict__ beta,
                                               const float* __restrict__ delta,
                                               void* __restrict__ wsv) {
  u64* RK = (u64*)wsv + RK_O;
  u64* CT = (u64*)wsv + CT_O;
  u64* HD = (u64*)wsv + HD_O;
  float* base = (float*)wsv + BASE_F;

  const int tid = threadIdx.x;
  const float bb = beta[0];
  const float dN = delta[0] / 1024.0f;

  if (blockIdx.x > 0) {
    // ---------------- prep blocks ----------------
    const int g = (int)(blockIdx.x - 1) * 256 + tid;   // 0..7679
    const int c8 = g & 7;
    if (g < NSRC * 8) {
      int m = g >> 3;
      float myE = enh[128 + m], myI = inh[128 + m];
      int re = 0, ri = 0;
      for (int i = 112 * c8; i < 112 * c8 + 112; ++i) {
        float ev = enh[128 + i], iv = inh[128 + i];
        re += (ev < myE || (ev == myE && i < m)) ? 1 : 0;
        ri += (iv < myI || (iv == myI && i < m)) ? 1 : 0;
      }
      int p = re | (ri << 16);
      p += __shfl_xor(p, 1); p += __shfl_xor(p, 2); p += __shfl_xor(p, 4);
      if (c8 == 0) ast(&RK[m], ((u64)TAG_RK << 32) | (u32)p);
    }
    {
      int j = g >> 3;
      float cj = ident[64 + j];
      int ce = 0, ci = 0;
      for (int i = 112 * c8; i < 112 * c8 + 112; ++i) {
        ce += (enh[128 + i] <= cj) ? 1 : 0;
        ci += (inh[128 + i] <= cj) ? 1 : 0;
      }
      int p = ce | (ci << 16);
      p += __shfl_xor(p, 1); p += __shfl_xor(p, 2); p += __shfl_xor(p, 4);
      if (c8 == 0) ast(&CT[j], ((u64)TAG_CT << 32) | (u32)p);
    }
    {
      int j = g >> 3;
      float cj = ident[64 + j];
      float h = 0.0f;
      for (int k = 8 * c8; k < 8 * c8 + 8; ++k)
        h += expf(-bb * fabsf(enh[k] - cj)) - expf(-bb * fabsf(inh[k] - cj));
      h += __shfl_xor(h, 1); h += __shfl_xor(h, 2); h += __shfl_xor(h, 4);
      if (c8 == 0)
        ast(&HD[j], ((u64)TAG_HD << 32) |
                    (u64)__float_as_uint(dN * h * (1.0f / 1024.0f)));
    }
    return;
  }

  // ---------------- block 0: scan warmup ----------------
  __shared__ float yl[NJ];
  __shared__ float2 scanE[1024];
  __shared__ float2 scanI[1024];
  __shared__ float4 wtot[4];
  __shared__ float ssw[4];

  const int lane = tid & 63, wvid = tid >> 6;

  int rE[4], rI[4];
  if (tid < 224) {
    #pragma unroll
    for (int s = 0; s < 4; ++s) {
      u32 v = poll32(&RK[4 * tid + s], TAG_RK);
      rE[s] = v & 0xFFFF; rI[s] = v >> 16;
    }
  }
  int cE[4], cI[4];
  float hd[4], fm[4], fp[4];
  if (tid < 240) {
    #pragma unroll
    for (int c = 0; c < 4; ++c) {
      u32 v = poll32(&CT[4 * tid + c], TAG_CT);
      cE[c] = v & 0xFFFF; cI[c] = v >> 16;
      hd[c] = __uint_as_float(poll32(&HD[4 * tid + c], TAG_HD));
      float cj = ident[64 + 4 * tid + c];
      fm[c] = expf(-bb * cj); fp[c] = expf(bb * cj);
    }
  }
  float EP[4], EN[4], IP[4], IN2[4];
  if (tid < 224) {
    #pragma unroll
    for (int s = 0; s < 4; ++s) {
      float e = enh[128 + 4 * tid + s], i2 = inh[128 + 4 * tid + s];
      EP[s] = expf(bb * e);  EN[s] = expf(-bb * e);
      IP[s] = expf(bb * i2); IN2[s] = expf(-bb * i2);
    }
  }
  float y_own[4] = {1.0f / 1024.0f, 1.0f / 1024.0f, 1.0f / 1024.0f, 1.0f / 1024.0f};
  if (tid < 240) {
    #pragma unroll
    for (int c = 0; c < 4; ++c) yl[4 * tid + c] = 1.0f / 1024.0f;
  }
  __syncthreads();

  for (int t = 0; t <= NWARM; ++t) {
    if (tid == 0) {
      scanE[0] = make_float2(0.f, 0.f);
      scanI[0] = make_float2(0.f, 0.f);
    }
    if (tid >= 224) {
      #pragma unroll
      for (int c = 0; c < 4; ++c) {
        int p = 4 * tid + c;
        if (p > NSRC) {
          scanE[p] = make_float2(0.f, 0.f);
          scanI[p] = make_float2(0.f, 0.f);
        }
      }
    }
    if (tid < 224) {
      #pragma unroll
      for (int s = 0; s < 4; ++s) {
        float ym = yl[64 + 4 * tid + s];
        scanE[rE[s] + 1] = make_float2(ym * EP[s], ym * EN[s]);
        scanI[rI[s] + 1] = make_float2(ym * IP[s], ym * IN2[s]);
      }
    }
    __syncthreads();

    float2 e0 = scanE[4 * tid], e1 = scanE[4 * tid + 1],
           e2 = scanE[4 * tid + 2], e3 = scanE[4 * tid + 3];
    float2 i0 = scanI[4 * tid], i1 = scanI[4 * tid + 1],
           i2v = scanI[4 * tid + 2], i3 = scanI[4 * tid + 3];
    e1.x += e0.x; e1.y += e0.y; e2.x += e1.x; e2.y += e1.y; e3.x += e2.x; e3.y += e2.y;
    i1.x += i0.x; i1.y += i0.y; i2v.x += i1.x; i2v.y += i1.y; i3.x += i2v.x; i3.y += i2v.y;
    float4 tot = make_float4(e3.x, e3.y, i3.x, i3.y);
    float4 inc = tot;
    #pragma unroll
    for (int off = 1; off < 64; off <<= 1) {
      float ox = __shfl_up(inc.x, off, 64);
      float oy = __shfl_up(inc.y, off, 64);
      float oz = __shfl_up(inc.z, off, 64);
      float ow = __shfl_up(inc.w, off, 64);
      if (lane >= off) { inc.x += ox; inc.y += oy; inc.z += oz; inc.w += ow; }
    }
    if (lane == 63) wtot[wvid] = inc;
    __syncthreads();
    float4 exc = make_float4(inc.x - tot.x, inc.y - tot.y,
                             inc.z - tot.z, inc.w - tot.w);
    #pragma unroll
    for (int w = 0; w < 3; ++w)
      if (w < wvid) {
        float4 p = wtot[w];
        exc.x += p.x; exc.y += p.y; exc.z += p.z; exc.w += p.w;
      }
    e0.x += exc.x; e0.y += exc.y; e1.x += exc.x; e1.y += exc.y;
    e2.x += exc.x; e2.y += exc.y; e3.x += exc.x; e3.y += exc.y;
    i0.x += exc.z; i0.y += exc.w; i1.x += exc.z; i1.y += exc.w;
    i2v.x += exc.z; i2v.y += exc.w; i3.x += exc.z; i3.y += exc.w;
    scanE[4 * tid] = e0; scanE[4 * tid + 1] = e1;
    scanE[4 * tid + 2] = e2; scanE[4 * tid + 3] = e3;
    scanI[4 * tid] = i0; scanI[4 * tid + 1] = i1;
    scanI[4 * tid + 2] = i2v; scanI[4 * tid + 3] = i3;
    __syncthreads();

    float nv[4] = {0.f, 0.f, 0.f, 0.f};
    float psum = 0.0f;
    if (tid < 240) {
      float2 TE = scanE[NSRC], TI = scanI[NSRC];
      #pragma unroll
      for (int c = 0; c < 4; ++c) {
        float2 AE = scanE[cE[c]], AI = scanI[cI[c]];
        float dot = fm[c] * AE.x + fp[c] * (TE.y - AE.y)
                  - fm[c] * AI.x - fp[c] * (TI.y - AI.y);
        float pre = y_own[c] + dN * dot;
        if (t < NWARM) {
          nv[c] = fmaxf(pre + hd[c], 0.0f);
          psum += nv[c];
        } else {
          base[4 * tid + c] = pre;   // plain store; K2 reads after boundary
        }
      }
    }
    if (t < NWARM) {
      #pragma unroll
      for (int off = 32; off >= 1; off >>= 1) psum += __shfl_xor(psum, off);
      if (lane == 0) ssw[wvid] = psum;
      __syncthreads();
      float s = ssw[0] + ssw[1] + ssw[2] + ssw[3];
      float inv = (s > 0.0f) ? 1.0f / s : 1.0f;
      if (tid < 240) {
        #pragma unroll
        for (int c = 0; c < 4; ++c) {
          y_own[c] = nv[c] * inv;
          yl[4 * tid + c] = y_own[c];
        }
      }
    }
    __syncthreads();
  }
}

// K2: 256 blocks x 512 threads, 64 rows/block, 8x8 micro-tile (round-0 proven
// skeleton) with the fused-arc improvements:
//  - Wl recomputed in-LDS from the separable exp form (no Wk global traffic)
//  - lane-contiguous float4 Wl reads: 16B lane stride -> all 32 banks
//    (round-0's colg*8 pattern was 32B stride -> 4 banks -> 16-way conflict)
//  - base read plainly from ws (written by front_k; kernel boundary orders)
//  - output chunk (cols 0..511) processed LAST -> stores from live acc
__global__ __launch_bounds__(512) void batch_k(const float* __restrict__ inp,
                                               const float* __restrict__ ident,
                                               const float* __restrict__ enh,
                                               const float* __restrict__ inh,
                                               const float* __restrict__ beta,
                                               const float* __restrict__ delta,
                                               const float* __restrict__ ws,
                                               float* __restrict__ out) {
  __shared__ float At[64][66];     // round-0 proven transpose layout
  __shared__ float Wl[16][512];
  __shared__ float bch[NJ];
  __shared__ float4 Ek4[64];
  __shared__ float2 Ei2[64];

  const int tid = threadIdx.x;
  const int colg = tid & 63;
  const int rowg = tid >> 6;                 // 8 waves, 8 rows each
  const size_t rowbase = (size_t)blockIdx.x * 64;
  const float bb = beta[0];
  const float dN = delta[0] / 1024.0f;

  #pragma unroll
  for (int i = 0; i < 2; ++i) {
    int fi = tid + i * 512;
    int r = fi >> 4, c4 = (fi & 15) * 4;
    float4 f4 = *(const float4*)(inp + (rowbase + r) * 64 + c4);
    At[c4 + 0][r] = f4.x; At[c4 + 1][r] = f4.y;
    At[c4 + 2][r] = f4.z; At[c4 + 3][r] = f4.w;
  }
  if (tid < 64) {
    float e = enh[tid], iv = inh[tid];
    Ek4[tid] = make_float4(expf(bb * e), expf(-bb * e),
                           expf(bb * iv), expf(-bb * iv));
    Ei2[tid] = make_float2(e, iv);
  }
  if (tid < 240) {
    float4 b4 = *(const float4*)(ws + BASE_F + 4 * tid);
    bch[4 * tid + 0] = b4.x; bch[4 * tid + 1] = b4.y;
    bch[4 * tid + 2] = b4.z; bch[4 * tid + 3] = b4.w;
  }

  float acc[8][8];
  float rs[8];
  #pragma unroll
  for (int r = 0; r < 8; ++r) rs[r] = 0.0f;

  // Weights from the separable form:
  // exp(-b|e_k - c_j|) = (e_k >= c_j) ? e^{-b e_k} e^{+b c_j} : e^{+b e_k} e^{-b c_j}
  #pragma unroll 1
  for (int ch = 0; ch < 2; ++ch) {
    const int c0 = ch ? 0 : 512;             // output chunk (cols 0..511) last
    const bool ok = (c0 + tid) < NJ;         // chunk A: tid<448
    const float cj = ok ? ident[64 + c0 + tid] : 0.0f;
    const float fpc = expf(bb * cj), fmc = expf(-bb * cj);

    #pragma unroll
    for (int r = 0; r < 8; ++r)
      #pragma unroll
      for (int c = 0; c < 8; ++c) acc[r][c] = 0.0f;

    #pragma unroll 1
    for (int s = 0; s < 4; ++s) {
      __syncthreads();
      #pragma unroll 4
      for (int e = 0; e < 16; ++e) {
        int k = 16 * s + e;
        float4 E = Ek4[k];
        float2 ei = Ei2[k];
        float w = 0.0f;
        if (ok)
          w = dN * (((ei.x >= cj) ? E.y * fpc : E.x * fmc)
                  - ((ei.y >= cj) ? E.w * fpc : E.z * fmc));
        Wl[e][tid] = w;
      }
      __syncthreads();
      #pragma unroll
      for (int kk = 0; kk < 16; ++kk) {
        float4 a0 = *(const float4*)&At[16 * s + kk][rowg * 8];      // bcast
        float4 a1 = *(const float4*)&At[16 * s + kk][rowg * 8 + 4];  // bcast
        float4 w0 = *(const float4*)&Wl[kk][colg * 4];        // conflict-free
        float4 w1 = *(const float4*)&Wl[kk][256 + colg * 4];  // conflict-free
        float a_[8] = {a0.x, a0.y, a0.z, a0.w, a1.x, a1.y, a1.z, a1.w};
        float w_[8] = {w0.x, w0.y, w0.z, w0.w, w1.x, w1.y, w1.z, w1.w};
        #pragma unroll
        for (int r = 0; r < 8; ++r)
          #pragma unroll
          for (int c = 0; c < 8; ++c)
            acc[r][c] = fmaf(a_[r], w_[c], acc[r][c]);
      }
    }

    // per-chunk epilogue: relu row-sum (bias known from the start)
    #pragma unroll
    for (int c = 0; c < 8; ++c) {
      int cl = (c < 4) ? (colg * 4 + c) : (256 + colg * 4 + (c - 4));
      int j = c0 + cl;
      float bv = (j < NJ) ? bch[j] : -1.0e30f;   // acc is 0 there
      #pragma unroll
      for (int r = 0; r < 8; ++r)
        rs[r] += fmaxf(acc[r][c] + bv, 0.0f);
    }
  }

  #pragma unroll
  for (int r = 0; r < 8; ++r) {
    float v = rs[r];
    #pragma unroll
    for (int off = 32; off >= 1; off >>= 1) v += __shfl_xor(v, off);
    rs[r] = v;
  }
  // acc holds chunk cols 0..511; lanes colg<16 cover out cols 0..63 via
  // cl = colg*4 + c (c=0..3) -> acc[r][0..3].
  if (colg < 16) {
    #pragma unroll
    for (int r = 0; r < 8; ++r) {
      float inv = (rs[r] > 0.0f) ? 1.0f / rs[r] : 1.0f;
      float* op = out + (rowbase + rowg * 8 + r) * 64 + colg * 4;
      float4 o;
      o.x = fmaxf(acc[r][0] + bch[colg * 4 + 0], 0.0f) * inv;
      o.y = fmaxf(acc[r][1] + bch[colg * 4 + 1], 0.0f) * inv;
      o.z = fmaxf(acc[r][2] + bch[colg * 4 + 2], 0.0f) * inv;
      o.w = fmaxf(acc[r][3] + bch[colg * 4 + 3], 0.0f) * inv;
      *(float4*)op = o;
    }
  }
}

extern "C" void kernel_launch(void* const* d_in, const int* in_sizes, int n_in,
                              void* d_out, int out_size, void* d_ws, size_t ws_size,
                              hipStream_t stream) {
  const float* inp   = (const float*)d_in[0];
  const float* ident = (const float*)d_in[1];
  const float* enh   = (const float*)d_in[2];
  const float* inh   = (const float*)d_in[3];
  const float* beta  = (const float*)d_in[4];
  const float* delta = (const float*)d_in[5];

  hipLaunchKernelGGL(front_k, dim3(31), dim3(256), 0, stream,
                     ident, enh, inh, beta, delta, d_ws);
  hipLaunchKernelGGL(batch_k, dim3(256), dim3(512), 0, stream,
                     inp, ident, enh, inh, beta, delta,
                     (const float*)d_ws, (float*)d_out);
}

// Round 8
// 155.054 us; speedup vs baseline: 1.2856x; 1.0371x over previous
//
#include <hip/hip_runtime.h>
#include <math.h>

#define NJ 960           // tail columns (global 64..1023)
#define NSRC 896         // tail sources (global 128..1023)
#define NWARM 25

typedef unsigned long long u64;
typedef unsigned int u32;

// ws layout:
//   u64 idx: RK[896] tag|(rE|rI<<16), CT[960] tag|(cntE|cntI<<16),
//            HD[960] tag|float(hd[j])
//   float idx 8192 : Wk[64][960]  (built by front_k blocks 31..60)
//   float idx 69632: base[960]    (plain floats; K1->K2 kernel boundary orders)
#define RK_O 0u
#define CT_O 896u
#define HD_O 1856u
#define WK_F 8192u
#define BASE_F 69632u

#define TAG_RK 0x524B0001u
#define TAG_CT 0x43540001u
#define TAG_HD 0x48440001u

__device__ __forceinline__ void ast(u64* p, u64 v) {
  __hip_atomic_store(p, v, __ATOMIC_RELAXED, __HIP_MEMORY_SCOPE_AGENT);
}
__device__ __forceinline__ u64 ald(const u64* p) {
  return __hip_atomic_load(p, __ATOMIC_RELAXED, __HIP_MEMORY_SCOPE_AGENT);
}
__device__ __forceinline__ u32 poll32(const u64* p, u32 tag) {
  u64 v = ald(p);
  while ((u32)(v >> 32) != tag) { __builtin_amdgcn_s_sleep(1); v = ald(p); }
  return (u32)v;
}

// K1, grid 61:
//   block 0      : single-block scan warmup (round-7 proven, 62 us)
//   blocks 1..30 : prep A/B/C (ranks/counts/hd) — light, near the scan's CUs
//   blocks 31..60: part D (Wk table) — SEPARATE blocks so its heavy exp loops
//                  don't contend with the scan's CU (that contention was the
//                  80.8 -> 62.1 us delta between rounds 0 and 7)
__global__ __launch_bounds__(256) void front_k(const float* __restrict__ ident,
                                               const float* __restrict__ enh,
                                               const float* __restrict__ inh,
                                               const float* __restrict__ beta,
                                               const float* __restrict__ delta,
                                               void* __restrict__ wsv) {
  u64* RK = (u64*)wsv + RK_O;
  u64* CT = (u64*)wsv + CT_O;
  u64* HD = (u64*)wsv + HD_O;
  float* Wk = (float*)wsv + WK_F;
  float* base = (float*)wsv + BASE_F;

  const int tid = threadIdx.x;
  const float bb = beta[0];
  const float dN = delta[0] / 1024.0f;

  if (blockIdx.x > 30) {
    // ---------------- part D: Wk table (round-0 proven mapping) ----------
    const int g2 = (int)(blockIdx.x - 31) * 256 + tid;   // 0..7679
    int k = g2 / 120;
    int jb = (g2 % 120) * 8;
    float ek = enh[k], ik = inh[k];
    #pragma unroll
    for (int u = 0; u < 8; ++u) {
      float cj = ident[64 + jb + u];
      Wk[(size_t)k * NJ + jb + u] =
          dN * (expf(-bb * fabsf(ek - cj)) - expf(-bb * fabsf(ik - cj)));
    }
    return;
  }

  if (blockIdx.x > 0) {
    // ---------------- prep blocks (A/B/C) ----------------
    const int g = (int)(blockIdx.x - 1) * 256 + tid;   // 0..7679
    const int c8 = g & 7;
    if (g < NSRC * 8) {
      int m = g >> 3;
      float myE = enh[128 + m], myI = inh[128 + m];
      int re = 0, ri = 0;
      for (int i = 112 * c8; i < 112 * c8 + 112; ++i) {
        float ev = enh[128 + i], iv = inh[128 + i];
        re += (ev < myE || (ev == myE && i < m)) ? 1 : 0;
        ri += (iv < myI || (iv == myI && i < m)) ? 1 : 0;
      }
      int p = re | (ri << 16);
      p += __shfl_xor(p, 1); p += __shfl_xor(p, 2); p += __shfl_xor(p, 4);
      if (c8 == 0) ast(&RK[m], ((u64)TAG_RK << 32) | (u32)p);
    }
    {
      int j = g >> 3;
      float cj = ident[64 + j];
      int ce = 0, ci = 0;
      for (int i = 112 * c8; i < 112 * c8 + 112; ++i) {
        ce += (enh[128 + i] <= cj) ? 1 : 0;
        ci += (inh[128 + i] <= cj) ? 1 : 0;
      }
      int p = ce | (ci << 16);
      p += __shfl_xor(p, 1); p += __shfl_xor(p, 2); p += __shfl_xor(p, 4);
      if (c8 == 0) ast(&CT[j], ((u64)TAG_CT << 32) | (u32)p);
    }
    {
      int j = g >> 3;
      float cj = ident[64 + j];
      float h = 0.0f;
      for (int k = 8 * c8; k < 8 * c8 + 8; ++k)
        h += expf(-bb * fabsf(enh[k] - cj)) - expf(-bb * fabsf(inh[k] - cj));
      h += __shfl_xor(h, 1); h += __shfl_xor(h, 2); h += __shfl_xor(h, 4);
      if (c8 == 0)
        ast(&HD[j], ((u64)TAG_HD << 32) |
                    (u64)__float_as_uint(dN * h * (1.0f / 1024.0f)));
    }
    return;
  }

  // ---------------- block 0: scan warmup (proven, unchanged) ----------------
  __shared__ float yl[NJ];
  __shared__ float2 scanE[1024];
  __shared__ float2 scanI[1024];
  __shared__ float4 wtot[4];
  __shared__ float ssw[4];

  const int lane = tid & 63, wvid = tid >> 6;

  int rE[4], rI[4];
  if (tid < 224) {
    #pragma unroll
    for (int s = 0; s < 4; ++s) {
      u32 v = poll32(&RK[4 * tid + s], TAG_RK);
      rE[s] = v & 0xFFFF; rI[s] = v >> 16;
    }
  }
  int cE[4], cI[4];
  float hd[4], fm[4], fp[4];
  if (tid < 240) {
    #pragma unroll
    for (int c = 0; c < 4; ++c) {
      u32 v = poll32(&CT[4 * tid + c], TAG_CT);
      cE[c] = v & 0xFFFF; cI[c] = v >> 16;
      hd[c] = __uint_as_float(poll32(&HD[4 * tid + c], TAG_HD));
      float cj = ident[64 + 4 * tid + c];
      fm[c] = expf(-bb * cj); fp[c] = expf(bb * cj);
    }
  }
  float EP[4], EN[4], IP[4], IN2[4];
  if (tid < 224) {
    #pragma unroll
    for (int s = 0; s < 4; ++s) {
      float e = enh[128 + 4 * tid + s], i2 = inh[128 + 4 * tid + s];
      EP[s] = expf(bb * e);  EN[s] = expf(-bb * e);
      IP[s] = expf(bb * i2); IN2[s] = expf(-bb * i2);
    }
  }
  float y_own[4] = {1.0f / 1024.0f, 1.0f / 1024.0f, 1.0f / 1024.0f, 1.0f / 1024.0f};
  if (tid < 240) {
    #pragma unroll
    for (int c = 0; c < 4; ++c) yl[4 * tid + c] = 1.0f / 1024.0f;
  }
  __syncthreads();

  for (int t = 0; t <= NWARM; ++t) {
    if (tid == 0) {
      scanE[0] = make_float2(0.f, 0.f);
      scanI[0] = make_float2(0.f, 0.f);
    }
    if (tid >= 224) {
      #pragma unroll
      for (int c = 0; c < 4; ++c) {
        int p = 4 * tid + c;
        if (p > NSRC) {
          scanE[p] = make_float2(0.f, 0.f);
          scanI[p] = make_float2(0.f, 0.f);
        }
      }
    }
    if (tid < 224) {
      #pragma unroll
      for (int s = 0; s < 4; ++s) {
        float ym = yl[64 + 4 * tid + s];
        scanE[rE[s] + 1] = make_float2(ym * EP[s], ym * EN[s]);
        scanI[rI[s] + 1] = make_float2(ym * IP[s], ym * IN2[s]);
      }
    }
    __syncthreads();

    float2 e0 = scanE[4 * tid], e1 = scanE[4 * tid + 1],
           e2 = scanE[4 * tid + 2], e3 = scanE[4 * tid + 3];
    float2 i0 = scanI[4 * tid], i1 = scanI[4 * tid + 1],
           i2v = scanI[4 * tid + 2], i3 = scanI[4 * tid + 3];
    e1.x += e0.x; e1.y += e0.y; e2.x += e1.x; e2.y += e1.y; e3.x += e2.x; e3.y += e2.y;
    i1.x += i0.x; i1.y += i0.y; i2v.x += i1.x; i2v.y += i1.y; i3.x += i2v.x; i3.y += i2v.y;
    float4 tot = make_float4(e3.x, e3.y, i3.x, i3.y);
    float4 inc = tot;
    #pragma unroll
    for (int off = 1; off < 64; off <<= 1) {
      float ox = __shfl_up(inc.x, off, 64);
      float oy = __shfl_up(inc.y, off, 64);
      float oz = __shfl_up(inc.z, off, 64);
      float ow = __shfl_up(inc.w, off, 64);
      if (lane >= off) { inc.x += ox; inc.y += oy; inc.z += oz; inc.w += ow; }
    }
    if (lane == 63) wtot[wvid] = inc;
    __syncthreads();
    float4 exc = make_float4(inc.x - tot.x, inc.y - tot.y,
                             inc.z - tot.z, inc.w - tot.w);
    #pragma unroll
    for (int w = 0; w < 3; ++w)
      if (w < wvid) {
        float4 p = wtot[w];
        exc.x += p.x; exc.y += p.y; exc.z += p.z; exc.w += p.w;
      }
    e0.x += exc.x; e0.y += exc.y; e1.x += exc.x; e1.y += exc.y;
    e2.x += exc.x; e2.y += exc.y; e3.x += exc.x; e3.y += exc.y;
    i0.x += exc.z; i0.y += exc.w; i1.x += exc.z; i1.y += exc.w;
    i2v.x += exc.z; i2v.y += exc.w; i3.x += exc.z; i3.y += exc.w;
    scanE[4 * tid] = e0; scanE[4 * tid + 1] = e1;
    scanE[4 * tid + 2] = e2; scanE[4 * tid + 3] = e3;
    scanI[4 * tid] = i0; scanI[4 * tid + 1] = i1;
    scanI[4 * tid + 2] = i2v; scanI[4 * tid + 3] = i3;
    __syncthreads();

    float nv[4] = {0.f, 0.f, 0.f, 0.f};
    float psum = 0.0f;
    if (tid < 240) {
      float2 TE = scanE[NSRC], TI = scanI[NSRC];
      #pragma unroll
      for (int c = 0; c < 4; ++c) {
        float2 AE = scanE[cE[c]], AI = scanI[cI[c]];
        float dot = fm[c] * AE.x + fp[c] * (TE.y - AE.y)
                  - fm[c] * AI.x - fp[c] * (TI.y - AI.y);
        float pre = y_own[c] + dN * dot;
        if (t < NWARM) {
          nv[c] = fmaxf(pre + hd[c], 0.0f);
          psum += nv[c];
        } else {
          base[4 * tid + c] = pre;   // plain store; K2 reads after boundary
        }
      }
    }
    if (t < NWARM) {
      #pragma unroll
      for (int off = 32; off >= 1; off >>= 1) psum += __shfl_xor(psum, off);
      if (lane == 0) ssw[wvid] = psum;
      __syncthreads();
      float s = ssw[0] + ssw[1] + ssw[2] + ssw[3];
      float inv = (s > 0.0f) ? 1.0f / s : 1.0f;
      if (tid < 240) {
        #pragma unroll
        for (int c = 0; c < 4; ++c) {
          y_own[c] = nv[c] * inv;
          yl[4 * tid + c] = y_own[c];
        }
      }
    }
    __syncthreads();
  }
}

// K2: 512 blocks x 512 threads, 32 rows/block -> all 256 CUs at 2 blocks/CU
// (round-0/7's grid 256 left half the chip idle: ~52 KB LDS = 2 blocks/CU
// over only 128 CUs). Per-thread: acc[4][8] per chunk, 4096 FMA total
// (full-chip floor 13.7 us). Weights streamed from the precomputed Wk table
// (L2-resident, built free under the scan); lane-contiguous conflict-free Wl
// reads; At padded to [64][36] for 16B-aligned b128 reads; output chunk
// (cols 0..511) processed last -> stores from live acc.
__global__ __launch_bounds__(512) void batch_k(const float* __restrict__ inp,
                                               const float* __restrict__ ws,
                                               float* __restrict__ out) {
  __shared__ float At[64][36];
  __shared__ float Wl[16][512];
  __shared__ float bch[NJ];

  const int tid = threadIdx.x;
  const int colg = tid & 63;
  const int rowg = tid >> 6;                 // 8 waves, 4 rows each
  const size_t rowbase = (size_t)blockIdx.x * 32;
  const float* __restrict__ Wk = ws + WK_F;

  {
    int r = tid >> 4, c4 = (tid & 15) * 4;   // 32 rows x 16 quads
    float4 f4 = *(const float4*)(inp + (rowbase + r) * 64 + c4);
    At[c4 + 0][r] = f4.x; At[c4 + 1][r] = f4.y;
    At[c4 + 2][r] = f4.z; At[c4 + 3][r] = f4.w;
  }
  if (tid < 240) {
    float4 b4 = *(const float4*)(ws + BASE_F + 4 * tid);
    bch[4 * tid + 0] = b4.x; bch[4 * tid + 1] = b4.y;
    bch[4 * tid + 2] = b4.z; bch[4 * tid + 3] = b4.w;
  }

  float acc[4][8];
  float rs[4] = {0.f, 0.f, 0.f, 0.f};

  #pragma unroll 1
  for (int ch = 0; ch < 2; ++ch) {
    const int c0 = ch ? 0 : 512;             // output chunk (cols 0..511) last

    #pragma unroll
    for (int r = 0; r < 4; ++r)
      #pragma unroll
      for (int c = 0; c < 8; ++c) acc[r][c] = 0.0f;

    #pragma unroll 1
    for (int s = 0; s < 4; ++s) {
      __syncthreads();
      #pragma unroll
      for (int i = 0; i < 4; ++i) {          // stage 16x512 Wl from Wk (L2)
        int fi = tid + i * 512;              // 0..2047
        int kk = fi >> 7;                    // 0..15
        int c4 = (fi & 127) * 4;             // 0..508
        int j = c0 + c4;
        float4 v = make_float4(0.f, 0.f, 0.f, 0.f);
        if (j < NJ)                          // j mult of 4 -> j<=956 full quad
          v = *(const float4*)(Wk + (size_t)(16 * s + kk) * NJ + j);
        *(float4*)&Wl[kk][c4] = v;
      }
      __syncthreads();
      #pragma unroll
      for (int kk = 0; kk < 16; ++kk) {
        float4 av = *(const float4*)&At[16 * s + kk][rowg * 4];  // bcast
        float4 w0 = *(const float4*)&Wl[kk][colg * 4];        // conflict-free
        float4 w1 = *(const float4*)&Wl[kk][256 + colg * 4];  // conflict-free
        float a_[4] = {av.x, av.y, av.z, av.w};
        float w_[8] = {w0.x, w0.y, w0.z, w0.w, w1.x, w1.y, w1.z, w1.w};
        #pragma unroll
        for (int r = 0; r < 4; ++r)
          #pragma unroll
          for (int c = 0; c < 8; ++c)
            acc[r][c] = fmaf(a_[r], w_[c], acc[r][c]);
      }
    }

    // per-chunk epilogue: relu row-sum (bias known from the start)
    #pragma unroll
    for (int c = 0; c < 8; ++c) {
      int cl = (c < 4) ? (colg * 4 + c) : (256 + colg * 4 + (c - 4));
      int j = c0 + cl;
      float bv = (j < NJ) ? bch[j] : -1.0e30f;   // acc is 0 there
      #pragma unroll
      for (int r = 0; r < 4; ++r)
        rs[r] += fmaxf(acc[r][c] + bv, 0.0f);
    }
  }

  #pragma unroll
  for (int r = 0; r < 4; ++r) {
    float v = rs[r];
    #pragma unroll
    for (int off = 32; off >= 1; off >>= 1) v += __shfl_xor(v, off);
    rs[r] = v;
  }
  // acc holds chunk cols 0..511; lanes colg<16 cover out cols 0..63 via
  // cl = colg*4 + c (c=0..3) -> acc[r][0..3].
  if (colg < 16) {
    #pragma unroll
    for (int r = 0; r < 4; ++r) {
      float inv = (rs[r] > 0.0f) ? 1.0f / rs[r] : 1.0f;
      float* op = out + (rowbase + rowg * 4 + r) * 64 + colg * 4;
      float4 o;
      o.x = fmaxf(acc[r][0] + bch[colg * 4 + 0], 0.0f) * inv;
      o.y = fmaxf(acc[r][1] + bch[colg * 4 + 1], 0.0f) * inv;
      o.z = fmaxf(acc[r][2] + bch[colg * 4 + 2], 0.0f) * inv;
      o.w = fmaxf(acc[r][3] + bch[colg * 4 + 3], 0.0f) * inv;
      *(float4*)op = o;
    }
  }
}

extern "C" void kernel_launch(void* const* d_in, const int* in_sizes, int n_in,
                              void* d_out, int out_size, void* d_ws, size_t ws_size,
                              hipStream_t stream) {
  const float* inp   = (const float*)d_in[0];
  const float* ident = (const float*)d_in[1];
  const float* enh   = (const float*)d_in[2];
  const float* inh   = (const float*)d_in[3];
  const float* beta  = (const float*)d_in[4];
  const float* delta = (const float*)d_in[5];

  hipLaunchKernelGGL(front_k, dim3(61), dim3(256), 0, stream,
                     ident, enh, inh, beta, delta, d_ws);
  hipLaunchKernelGGL(batch_k, dim3(512), dim3(512), 0, stream,
                     inp, (const float*)d_ws, (float*)d_out);
}